// Round 7
// baseline (1375.816 us; speedup 1.0000x reference)
//
#include <hip/hip_runtime.h>
#include <hip/hip_bf16.h>
#include <hip/hip_fp16.h>

#define N_NODES 50000
#define N_EDGES 800000
#define NNIN    128
#define NOPEN   64
#define NUM_OUT 40
#define NLAYER  8
#define H2      0.01f

#define SCAN_BLOCKS ((N_NODES + 255) / 256)   // 196

// tanh(x) = 1 - 2/(exp(2x)+1); |rel err| ~1e-6.
__device__ __forceinline__ float ftanh(float x) {
    float e2 = __expf(2.0f * x);
    return 1.0f - 2.0f * __builtin_amdgcn_rcpf(e2 + 1.0f);
}

// ---- prep: degree for GCN norm (J-based + self-loop) -------------------

__global__ void deg_init(int* __restrict__ degi, int* __restrict__ deg2) {
    int n = blockIdx.x * 256 + threadIdx.x;
    if (n < N_NODES) { degi[n] = 1; deg2[n] = 0; }
}

__global__ void deg_count(const int* __restrict__ I, const int* __restrict__ J,
                          int* __restrict__ degi, int* __restrict__ deg2) {
    int e = blockIdx.x * 256 + threadIdx.x;
    if (e < N_EDGES) {
        atomicAdd(&degi[J[e]], 1);      // norm degree (reference: segment_sum over J2)
        atomicAdd(&deg2[I[e]], 1);      // structural degree, both directions
        atomicAdd(&deg2[J[e]], 1);
    }
}

__global__ void calc_dinv(const int* __restrict__ degi, float* __restrict__ dinv) {
    int n = blockIdx.x * 256 + threadIdx.x;
    if (n < N_NODES) dinv[n] = rsqrtf((float)degi[n]);
}

// ---- hierarchical exclusive scan of deg2 -> row_start ------------------

__global__ __launch_bounds__(256) void scan1(const int* __restrict__ deg2,
                                             int* __restrict__ row_start,
                                             int* __restrict__ block_sums) {
    __shared__ int sh[256];
    int t = threadIdx.x, n = blockIdx.x * 256 + t;
    int v = (n < N_NODES) ? deg2[n] : 0;
    sh[t] = v;
    __syncthreads();
#pragma unroll
    for (int off = 1; off < 256; off <<= 1) {
        int x = (t >= off) ? sh[t - off] : 0;
        __syncthreads();
        sh[t] += x;
        __syncthreads();
    }
    if (n < N_NODES) row_start[n] = sh[t] - v;  // exclusive
    if (t == 255) block_sums[blockIdx.x] = sh[t];
}

__global__ __launch_bounds__(256) void scan2(int* __restrict__ block_sums,
                                             int* __restrict__ block_off) {
    __shared__ int sh[256];
    int t = threadIdx.x;
    int v = (t < SCAN_BLOCKS) ? block_sums[t] : 0;
    sh[t] = v;
    __syncthreads();
#pragma unroll
    for (int off = 1; off < 256; off <<= 1) {
        int x = (t >= off) ? sh[t - off] : 0;
        __syncthreads();
        sh[t] += x;
        __syncthreads();
    }
    if (t < SCAN_BLOCKS) block_off[t] = sh[t] - v;  // exclusive
}

__global__ __launch_bounds__(256) void scan3(int* __restrict__ row_start,
                                             const int* __restrict__ block_off,
                                             int* __restrict__ cursor) {
    int t = threadIdx.x, n = blockIdx.x * 256 + t;
    if (n < N_NODES) {
        int r = row_start[n] + block_off[blockIdx.x];
        row_start[n] = r;
        cursor[n] = r;
    }
}

// ---- fill CSR entries: (other_node, W) per directed incidence ----------

__global__ void fill_ent(const int* __restrict__ I, const int* __restrict__ J,
                         const float* __restrict__ dinv,
                         int* __restrict__ cursor, int2* __restrict__ ent) {
    int e = blockIdx.x * 256 + threadIdx.x;
    if (e >= N_EDGES) return;
    int i = I[e], j = J[e];
    float w = dinv[i] * dinv[j];
    int wb = __float_as_int(w);
    int p1 = atomicAdd(&cursor[i], 1);
    ent[p1] = make_int2(j, wb);
    int p2 = atomicAdd(&cursor[j], 1);
    ent[p2] = make_int2(i, wb);
}

// ---- first layer: x = relu(K1 @ xn_in), xn_in is (128, N) f32 ----------
// out layout node-major: x[n*64 + o]
__global__ __launch_bounds__(256) void first_layer(const float* __restrict__ xn,
                                                   const float* __restrict__ k1f,
                                                   float* __restrict__ x_cur,
                                                   float* __restrict__ x_old) {
    __shared__ float Ks[NOPEN * 129];
    __shared__ float xs[32 * 64];
    int t = threadIdx.x;
    int n0 = blockIdx.x * 64;
    for (int idx = t; idx < NOPEN * NNIN; idx += 256)
        Ks[(idx >> 7) * 129 + (idx & 127)] = k1f[idx];

    int tn = t & 15, to = t >> 4;
    float acc[4][4] = {};
    for (int c0 = 0; c0 < NNIN; c0 += 32) {
        __syncthreads();
        for (int idx = t; idx < 32 * 64; idx += 256) {
            int ci = idx >> 6, n = idx & 63;
            int gn = n0 + n;
            xs[ci * 64 + n] = (gn < N_NODES) ? xn[(size_t)(c0 + ci) * N_NODES + gn] : 0.f;
        }
        __syncthreads();
        for (int ci = 0; ci < 32; ci++) {
            float xv[4], kv[4];
#pragma unroll
            for (int i2 = 0; i2 < 4; i2++) xv[i2] = xs[ci * 64 + tn * 4 + i2];
#pragma unroll
            for (int j = 0; j < 4; j++) kv[j] = Ks[(to * 4 + j) * 129 + c0 + ci];
#pragma unroll
            for (int i2 = 0; i2 < 4; i2++)
#pragma unroll
                for (int j = 0; j < 4; j++) acc[i2][j] += xv[i2] * kv[j];
        }
    }
#pragma unroll
    for (int i2 = 0; i2 < 4; i2++) {
        int node = n0 + tn * 4 + i2;
        if (node < N_NODES) {
            float4 st;
            st.x = fmaxf(acc[i2][0], 0.f);
            st.y = fmaxf(acc[i2][1], 0.f);
            st.z = fmaxf(acc[i2][2], 0.f);
            st.w = fmaxf(acc[i2][3], 0.f);
            *(float4*)&x_cur[(size_t)node * 64 + to * 4] = st;
            *(float4*)&x_old[(size_t)node * 64 + to * 4] = st;
        }
    }
}

// ---- Y[n][o] = sum_c K[o][c] * x[n][c], output fp16 --------------------
__global__ __launch_bounds__(256) void mat_y(const float* __restrict__ x,
                                             const float* __restrict__ K,
                                             __half* __restrict__ Y) {
    __shared__ float Ks[64 * 65];
    __shared__ float xs[64 * 65];
    int t = threadIdx.x, n0 = blockIdx.x * 64;
    for (int idx = t; idx < 4096; idx += 256) {
        int r = idx >> 6, c = idx & 63;
        Ks[r * 65 + c] = K[idx];
        int gn = n0 + r;
        xs[r * 65 + c] = (gn < N_NODES) ? x[(size_t)gn * 64 + c] : 0.f;
    }
    __syncthreads();
    int tn = t & 15, to = t >> 4;
    float acc[4][4] = {};
    for (int c = 0; c < 64; c++) {
        float xv[4], kv[4];
#pragma unroll
        for (int i2 = 0; i2 < 4; i2++) xv[i2] = xs[(tn * 4 + i2) * 65 + c];
#pragma unroll
        for (int j = 0; j < 4; j++) kv[j] = Ks[(to * 4 + j) * 65 + c];
#pragma unroll
        for (int i2 = 0; i2 < 4; i2++)
#pragma unroll
            for (int j = 0; j < 4; j++) acc[i2][j] += xv[i2] * kv[j];
    }
#pragma unroll
    for (int i2 = 0; i2 < 4; i2++) {
        int node = n0 + tn * 4 + i2;
        if (node < N_NODES) {
            __half2 h0 = __floats2half2_rn(acc[i2][0], acc[i2][1]);
            __half2 h1 = __floats2half2_rn(acc[i2][2], acc[i2][3]);
            __half2* dst = (__half2*)&Y[(size_t)node * 64 + to * 4];
            dst[0] = h0;
            dst[1] = h1;
        }
    }
}

// ---- fused gather + update: 2 waves per node, 2 nodes per 256-block ----
// Wave wv handles node blockIdx*2 + (wv>>1), adjacency half (wv&1).
// All 4 Ss rows are written by the block's 4 waves (R5 bug: assumed 8).
//   S_n[o]   = sum_{(n->other,W)} W * tanh(W*(Y_n[o] - Y_other[o]))
//   x_new[c] = 2*x_cur[c] - x_old[c] - H2 * sum_o K[c][o] * S_n[o]
__global__ __launch_bounds__(256) void gather_update(const __half* __restrict__ Y,
                                                     const float* __restrict__ x_cur,
                                                     const float* __restrict__ x_old,
                                                     const int2* __restrict__ ent,
                                                     const int* __restrict__ row_start,
                                                     const int* __restrict__ deg2,
                                                     const float* __restrict__ K,
                                                     float* __restrict__ x_out) {
    __shared__ float Ks[64 * 65];   // K[c][o] at Ks[c*65+o]
    __shared__ float Ss[4][64];
    int t = threadIdx.x;
    for (int idx = t; idx < 4096; idx += 256)
        Ks[(idx >> 6) * 65 + (idx & 63)] = K[idx];

    int wv = t >> 6, lane = t & 63;
    int node = blockIdx.x * 2 + (wv >> 1);
    int half = wv & 1;
    float s = 0.f;
    if (node < N_NODES) {
        float yn = __half2float(Y[(size_t)node * 64 + lane]);
        int beg = row_start[node];
        int d   = deg2[node];
        int mid = beg + ((d + 1) >> 1);
        int end = beg + d;
        int k  = half ? mid : beg;
        int k1 = half ? end : mid;
        for (; k + 3 < k1; k += 4) {
            int2 e0 = ent[k];
            int2 e1 = ent[k + 1];
            int2 e2 = ent[k + 2];
            int2 e3 = ent[k + 3];
            float y0 = __half2float(Y[(size_t)e0.x * 64 + lane]);
            float y1 = __half2float(Y[(size_t)e1.x * 64 + lane]);
            float y2 = __half2float(Y[(size_t)e2.x * 64 + lane]);
            float y3 = __half2float(Y[(size_t)e3.x * 64 + lane]);
            float w0 = __int_as_float(e0.y);
            float w1 = __int_as_float(e1.y);
            float w2 = __int_as_float(e2.y);
            float w3 = __int_as_float(e3.y);
            s += w0 * ftanh(w0 * (yn - y0));
            s += w1 * ftanh(w1 * (yn - y1));
            s += w2 * ftanh(w2 * (yn - y2));
            s += w3 * ftanh(w3 * (yn - y3));
        }
        for (; k < k1; k++) {
            int2 e0 = ent[k];
            float w0 = __int_as_float(e0.y);
            float y0 = __half2float(Y[(size_t)e0.x * 64 + lane]);
            s += w0 * ftanh(w0 * (yn - y0));
        }
    }
    Ss[wv][lane] = s;      // unconditional: all 4 rows valid
    __syncthreads();
    if (wv < 2) {
        int n = blockIdx.x * 2 + wv;
        if (n < N_NODES) {
            float acc = 0.f;
#pragma unroll 8
            for (int o = 0; o < 64; o++)
                acc += Ks[lane * 65 + o] * (Ss[2 * wv][o] + Ss[2 * wv + 1][o]);
            float xc = x_cur[(size_t)n * 64 + lane];
            float xo = x_old[(size_t)n * 64 + lane];
            x_out[(size_t)n * 64 + lane] = 2.f * xc - xo - H2 * acc;
        }
    }
}

// ---- out[n][o] = sum_c KNc[o][c] * x[n][c]; out is (N,40) f32 ----------
__global__ __launch_bounds__(256) void out_kernel(const float* __restrict__ x,
                                                  const float* __restrict__ Kc,
                                                  float* __restrict__ out) {
    __shared__ float xs[64 * 65];
    __shared__ float Ks[40 * 65];
    int t = threadIdx.x, n0 = blockIdx.x * 64;
    for (int idx = t; idx < 4096; idx += 256) {
        int r = idx >> 6, c = idx & 63;
        int gn = n0 + r;
        xs[r * 65 + c] = (gn < N_NODES) ? x[(size_t)gn * 64 + c] : 0.f;
    }
    for (int idx = t; idx < NUM_OUT * 64; idx += 256) {
        int r = idx >> 6, c = idx & 63;
        Ks[r * 65 + c] = Kc[idx];
    }
    __syncthreads();
    if (t < 160) {
        int tn = t & 15, to = t >> 4;
        float acc[4][4] = {};
        for (int c = 0; c < 64; c++) {
            float xv[4], kv[4];
#pragma unroll
            for (int i2 = 0; i2 < 4; i2++) xv[i2] = xs[(tn * 4 + i2) * 65 + c];
#pragma unroll
            for (int j = 0; j < 4; j++) kv[j] = Ks[(to * 4 + j) * 65 + c];
#pragma unroll
            for (int i2 = 0; i2 < 4; i2++)
#pragma unroll
                for (int j = 0; j < 4; j++) acc[i2][j] += xv[i2] * kv[j];
        }
#pragma unroll
        for (int i2 = 0; i2 < 4; i2++) {
            int node = n0 + tn * 4 + i2;
            if (node < N_NODES) {
#pragma unroll
                for (int j = 0; j < 4; j++)
                    out[(size_t)node * NUM_OUT + to * 4 + j] = acc[i2][j];
            }
        }
    }
}

extern "C" void kernel_launch(void* const* d_in, const int* in_sizes, int n_in,
                              void* d_out, int out_size, void* d_ws, size_t ws_size,
                              hipStream_t stream) {
    const float* xn = (const float*)d_in[0];
    const int*   I  = (const int*)d_in[1];
    const int*   J  = (const int*)d_in[2];
    const float* K1 = (const float*)d_in[4];
    const float* K2 = (const float*)d_in[5];
    const float* Kc = (const float*)d_in[6];

    const size_t NC = (size_t)N_NODES * NOPEN;  // 3.2M
    float*  f      = (float*)d_ws;
    float*  x_cur  = f;
    float*  x_old  = f + NC;
    __half* Y      = (__half*)(f + 2 * NC);     // 3.2M halves = 6.4 MB
    float*  dinv   = f + 2 * NC + NC / 2;       // after Y (NC halves = NC/2 floats)
    int*    degi   = (int*)(dinv + N_NODES);
    int*    deg2   = degi + N_NODES;
    int*    row_st = deg2 + N_NODES;
    int*    cursor = row_st + N_NODES;
    int*    bsums  = cursor + N_NODES;
    int*    boff   = bsums + 256;
    int2*   ent    = (int2*)(boff + 256);       // 1.6M entries = 12.8 MB

    dim3 B(256);
    const int GN = (N_NODES + 255) / 256;   // 196
    const int GE = (N_EDGES + 255) / 256;

    deg_init<<<GN, B, 0, stream>>>(degi, deg2);
    deg_count<<<GE, B, 0, stream>>>(I, J, degi, deg2);
    calc_dinv<<<GN, B, 0, stream>>>(degi, dinv);
    scan1<<<SCAN_BLOCKS, B, 0, stream>>>(deg2, row_st, bsums);
    scan2<<<1, B, 0, stream>>>(bsums, boff);
    scan3<<<SCAN_BLOCKS, B, 0, stream>>>(row_st, boff, cursor);
    fill_ent<<<GE, B, 0, stream>>>(I, J, dinv, cursor, ent);

    const int NB = (N_NODES + 63) / 64;     // 782
    first_layer<<<NB, B, 0, stream>>>(xn, K1, x_cur, x_old);

    float* xc = x_cur;
    float* xo = x_old;
    for (int l = 0; l < NLAYER; l++) {
        mat_y<<<NB, B, 0, stream>>>(xc, K2 + l * NOPEN * NOPEN, Y);
        gather_update<<<(N_NODES + 1) / 2, B, 0, stream>>>(Y, xc, xo, ent, row_st, deg2,
                                                           K2 + l * NOPEN * NOPEN, xo);
        float* tmp = xc; xc = xo; xo = tmp;
    }
    out_kernel<<<NB, B, 0, stream>>>(xc, Kc, (float*)d_out);
}

// Round 8
// 1121.433 us; speedup vs baseline: 1.2268x; 1.2268x over previous
//
#include <hip/hip_runtime.h>
#include <hip/hip_bf16.h>
#include <hip/hip_fp16.h>

#define N_NODES 50000
#define N_EDGES 800000
#define NNIN    128
#define NOPEN   64
#define NUM_OUT 40
#define NLAYER  8
#define H2      0.01f

#define SCAN_BLOCKS ((N_NODES + 255) / 256)   // 196

// tanh(x) = 1 - 2/(exp(2x)+1); |rel err| ~1e-6.
__device__ __forceinline__ float ftanh(float x) {
    float e2 = __expf(2.0f * x);
    return 1.0f - 2.0f * __builtin_amdgcn_rcpf(e2 + 1.0f);
}

// ---- prep: degree for GCN norm (J-based + self-loop) -------------------

__global__ void deg_init(int* __restrict__ degi, int* __restrict__ deg2) {
    int n = blockIdx.x * 256 + threadIdx.x;
    if (n < N_NODES) { degi[n] = 1; deg2[n] = 0; }
}

__global__ void deg_count(const int* __restrict__ I, const int* __restrict__ J,
                          int* __restrict__ degi, int* __restrict__ deg2) {
    int e = blockIdx.x * 256 + threadIdx.x;
    if (e < N_EDGES) {
        atomicAdd(&degi[J[e]], 1);      // norm degree (reference: segment_sum over J2)
        atomicAdd(&deg2[I[e]], 1);      // structural degree, both directions
        atomicAdd(&deg2[J[e]], 1);
    }
}

__global__ void calc_dinv(const int* __restrict__ degi, float* __restrict__ dinv) {
    int n = blockIdx.x * 256 + threadIdx.x;
    if (n < N_NODES) dinv[n] = rsqrtf((float)degi[n]);
}

// ---- hierarchical exclusive scan of PADDED deg2 -> row_start -----------
// rows padded to multiples of 4 so the gather's int4 entry loads are
// 16B-aligned (beg % 4 == 0 always).

__global__ __launch_bounds__(256) void scan1(const int* __restrict__ deg2,
                                             int* __restrict__ row_start,
                                             int* __restrict__ block_sums) {
    __shared__ int sh[256];
    int t = threadIdx.x, n = blockIdx.x * 256 + t;
    int v = (n < N_NODES) ? ((deg2[n] + 3) & ~3) : 0;
    sh[t] = v;
    __syncthreads();
#pragma unroll
    for (int off = 1; off < 256; off <<= 1) {
        int x = (t >= off) ? sh[t - off] : 0;
        __syncthreads();
        sh[t] += x;
        __syncthreads();
    }
    if (n < N_NODES) row_start[n] = sh[t] - v;  // exclusive
    if (t == 255) block_sums[blockIdx.x] = sh[t];
}

__global__ __launch_bounds__(256) void scan2(int* __restrict__ block_sums,
                                             int* __restrict__ block_off) {
    __shared__ int sh[256];
    int t = threadIdx.x;
    int v = (t < SCAN_BLOCKS) ? block_sums[t] : 0;
    sh[t] = v;
    __syncthreads();
#pragma unroll
    for (int off = 1; off < 256; off <<= 1) {
        int x = (t >= off) ? sh[t - off] : 0;
        __syncthreads();
        sh[t] += x;
        __syncthreads();
    }
    if (t < SCAN_BLOCKS) block_off[t] = sh[t] - v;  // exclusive
}

__global__ __launch_bounds__(256) void scan3(int* __restrict__ row_start,
                                             const int* __restrict__ block_off,
                                             int* __restrict__ cursor) {
    int t = threadIdx.x, n = blockIdx.x * 256 + t;
    if (n < N_NODES) {
        int r = row_start[n] + block_off[blockIdx.x];
        row_start[n] = r;
        cursor[n] = r;
    }
}

// ---- fill CSR entries: other-node index per directed incidence ---------

__global__ void fill_ent(const int* __restrict__ I, const int* __restrict__ J,
                         int* __restrict__ cursor, int* __restrict__ ent) {
    int e = blockIdx.x * 256 + threadIdx.x;
    if (e >= N_EDGES) return;
    int i = I[e], j = J[e];
    int p1 = atomicAdd(&cursor[i], 1);
    ent[p1] = j;
    int p2 = atomicAdd(&cursor[j], 1);
    ent[p2] = i;
}

// ---- first layer: x = relu(K1 @ xn_in), xn_in is (128, N) f32 ----------
// out layout node-major: x[n*64 + o]
__global__ __launch_bounds__(256) void first_layer(const float* __restrict__ xn,
                                                   const float* __restrict__ k1f,
                                                   float* __restrict__ x_cur,
                                                   float* __restrict__ x_old) {
    __shared__ float Ks[NOPEN * 129];
    __shared__ float xs[32 * 64];
    int t = threadIdx.x;
    int n0 = blockIdx.x * 64;
    for (int idx = t; idx < NOPEN * NNIN; idx += 256)
        Ks[(idx >> 7) * 129 + (idx & 127)] = k1f[idx];

    int tn = t & 15, to = t >> 4;
    float acc[4][4] = {};
    for (int c0 = 0; c0 < NNIN; c0 += 32) {
        __syncthreads();
        for (int idx = t; idx < 32 * 64; idx += 256) {
            int ci = idx >> 6, n = idx & 63;
            int gn = n0 + n;
            xs[ci * 64 + n] = (gn < N_NODES) ? xn[(size_t)(c0 + ci) * N_NODES + gn] : 0.f;
        }
        __syncthreads();
        for (int ci = 0; ci < 32; ci++) {
            float xv[4], kv[4];
#pragma unroll
            for (int i2 = 0; i2 < 4; i2++) xv[i2] = xs[ci * 64 + tn * 4 + i2];
#pragma unroll
            for (int j = 0; j < 4; j++) kv[j] = Ks[(to * 4 + j) * 129 + c0 + ci];
#pragma unroll
            for (int i2 = 0; i2 < 4; i2++)
#pragma unroll
                for (int j = 0; j < 4; j++) acc[i2][j] += xv[i2] * kv[j];
        }
    }
#pragma unroll
    for (int i2 = 0; i2 < 4; i2++) {
        int node = n0 + tn * 4 + i2;
        if (node < N_NODES) {
            float4 st;
            st.x = fmaxf(acc[i2][0], 0.f);
            st.y = fmaxf(acc[i2][1], 0.f);
            st.z = fmaxf(acc[i2][2], 0.f);
            st.w = fmaxf(acc[i2][3], 0.f);
            *(float4*)&x_cur[(size_t)node * 64 + to * 4] = st;
            *(float4*)&x_old[(size_t)node * 64 + to * 4] = st;
        }
    }
}

// ---- Y[n][o] = sum_c K[o][c] * x[n][c], output fp16 --------------------
__global__ __launch_bounds__(256) void mat_y(const float* __restrict__ x,
                                             const float* __restrict__ K,
                                             __half* __restrict__ Y) {
    __shared__ float Ks[64 * 65];
    __shared__ float xs[64 * 65];
    int t = threadIdx.x, n0 = blockIdx.x * 64;
    for (int idx = t; idx < 4096; idx += 256) {
        int r = idx >> 6, c = idx & 63;
        Ks[r * 65 + c] = K[idx];
        int gn = n0 + r;
        xs[r * 65 + c] = (gn < N_NODES) ? x[(size_t)gn * 64 + c] : 0.f;
    }
    __syncthreads();
    int tn = t & 15, to = t >> 4;
    float acc[4][4] = {};
    for (int c = 0; c < 64; c++) {
        float xv[4], kv[4];
#pragma unroll
        for (int i2 = 0; i2 < 4; i2++) xv[i2] = xs[(tn * 4 + i2) * 65 + c];
#pragma unroll
        for (int j = 0; j < 4; j++) kv[j] = Ks[(to * 4 + j) * 65 + c];
#pragma unroll
        for (int i2 = 0; i2 < 4; i2++)
#pragma unroll
            for (int j = 0; j < 4; j++) acc[i2][j] += xv[i2] * kv[j];
    }
#pragma unroll
    for (int i2 = 0; i2 < 4; i2++) {
        int node = n0 + tn * 4 + i2;
        if (node < N_NODES) {
            __half2 h0 = __floats2half2_rn(acc[i2][0], acc[i2][1]);
            __half2 h1 = __floats2half2_rn(acc[i2][2], acc[i2][3]);
            __half2* dst = (__half2*)&Y[(size_t)node * 64 + to * 4];
            dst[0] = h0;
            dst[1] = h1;
        }
    }
}

// ---- fused gather + update (R6 structure: 1 wave/node, 4 nodes/block) --
// Scalarized adjacency walk: bounds + entries wave-uniform (SGPR path).
//   w        = dinv[o] * dinv[n]          (bit-identical to fill-time W)
//   S_n[o]   = sum_edges W * tanh(W*(Y_n - Y_other))
//   x_new[c] = 2*x_cur[c] - x_old[c] - H2 * sum_o K[c][o] * S_n[o]
__global__ __launch_bounds__(256) void gather_update(const __half* __restrict__ Y,
                                                     const float* __restrict__ x_cur,
                                                     const float* __restrict__ x_old,
                                                     const int* __restrict__ ent,
                                                     const int* __restrict__ row_start,
                                                     const int* __restrict__ deg2,
                                                     const float* __restrict__ dinv,
                                                     const float* __restrict__ K,
                                                     float* __restrict__ x_out) {
    __shared__ float Ks[64 * 65];   // K[c][o] at Ks[c*65+o]
    __shared__ float Ss[4][64];
    int t = threadIdx.x;
    for (int idx = t; idx < 4096; idx += 256)
        Ks[(idx >> 6) * 65 + (idx & 63)] = K[idx];

    int wv = t >> 6, lane = t & 63;
    int n = blockIdx.x * 4 + wv;
    float s = 0.f;
    if (n < N_NODES) {
        float yn = __half2float(Y[(size_t)n * 64 + lane]);
        float vn = dinv[n];
        int beg = __builtin_amdgcn_readfirstlane(row_start[n]);  // % 4 == 0
        int d   = __builtin_amdgcn_readfirstlane(deg2[n]);
        int end = beg + d;
        int k = beg;
        for (; k + 3 < end; k += 4) {
            int4 oo = *(const int4*)&ent[k];               // 16B-aligned, uniform
            int o0 = __builtin_amdgcn_readfirstlane(oo.x);
            int o1 = __builtin_amdgcn_readfirstlane(oo.y);
            int o2 = __builtin_amdgcn_readfirstlane(oo.z);
            int o3 = __builtin_amdgcn_readfirstlane(oo.w);
            float y0 = __half2float(Y[((size_t)o0 << 6) + lane]);
            float y1 = __half2float(Y[((size_t)o1 << 6) + lane]);
            float y2 = __half2float(Y[((size_t)o2 << 6) + lane]);
            float y3 = __half2float(Y[((size_t)o3 << 6) + lane]);
            float w0 = dinv[o0] * vn;
            float w1 = dinv[o1] * vn;
            float w2 = dinv[o2] * vn;
            float w3 = dinv[o3] * vn;
            s += w0 * ftanh(w0 * (yn - y0));
            s += w1 * ftanh(w1 * (yn - y1));
            s += w2 * ftanh(w2 * (yn - y2));
            s += w3 * ftanh(w3 * (yn - y3));
        }
        for (; k < end; k++) {
            int o0 = __builtin_amdgcn_readfirstlane(ent[k]);
            float w0 = dinv[o0] * vn;
            float y0 = __half2float(Y[((size_t)o0 << 6) + lane]);
            s += w0 * ftanh(w0 * (yn - y0));
        }
    }
    Ss[wv][lane] = s;
    __syncthreads();
    if (n < N_NODES) {
        float acc = 0.f;
#pragma unroll 8
        for (int o = 0; o < 64; o++)
            acc += Ks[lane * 65 + o] * Ss[wv][o];   // 2-way bank alias (free) + broadcast
        float xc = x_cur[(size_t)n * 64 + lane];
        float xo = x_old[(size_t)n * 64 + lane];
        x_out[(size_t)n * 64 + lane] = 2.f * xc - xo - H2 * acc;
    }
}

// ---- out[n][o] = sum_c KNc[o][c] * x[n][c]; out is (N,40) f32 ----------
__global__ __launch_bounds__(256) void out_kernel(const float* __restrict__ x,
                                                  const float* __restrict__ Kc,
                                                  float* __restrict__ out) {
    __shared__ float xs[64 * 65];
    __shared__ float Ks[40 * 65];
    int t = threadIdx.x, n0 = blockIdx.x * 64;
    for (int idx = t; idx < 4096; idx += 256) {
        int r = idx >> 6, c = idx & 63;
        int gn = n0 + r;
        xs[r * 65 + c] = (gn < N_NODES) ? x[(size_t)gn * 64 + c] : 0.f;
    }
    for (int idx = t; idx < NUM_OUT * 64; idx += 256) {
        int r = idx >> 6, c = idx & 63;
        Ks[r * 65 + c] = Kc[idx];
    }
    __syncthreads();
    if (t < 160) {
        int tn = t & 15, to = t >> 4;
        float acc[4][4] = {};
        for (int c = 0; c < 64; c++) {
            float xv[4], kv[4];
#pragma unroll
            for (int i2 = 0; i2 < 4; i2++) xv[i2] = xs[(tn * 4 + i2) * 65 + c];
#pragma unroll
            for (int j = 0; j < 4; j++) kv[j] = Ks[(to * 4 + j) * 65 + c];
#pragma unroll
            for (int i2 = 0; i2 < 4; i2++)
#pragma unroll
                for (int j = 0; j < 4; j++) acc[i2][j] += xv[i2] * kv[j];
        }
#pragma unroll
        for (int i2 = 0; i2 < 4; i2++) {
            int node = n0 + tn * 4 + i2;
            if (node < N_NODES) {
#pragma unroll
                for (int j = 0; j < 4; j++)
                    out[(size_t)node * NUM_OUT + to * 4 + j] = acc[i2][j];
            }
        }
    }
}

extern "C" void kernel_launch(void* const* d_in, const int* in_sizes, int n_in,
                              void* d_out, int out_size, void* d_ws, size_t ws_size,
                              hipStream_t stream) {
    const float* xn = (const float*)d_in[0];
    const int*   I  = (const int*)d_in[1];
    const int*   J  = (const int*)d_in[2];
    const float* K1 = (const float*)d_in[4];
    const float* K2 = (const float*)d_in[5];
    const float* Kc = (const float*)d_in[6];

    const size_t NC = (size_t)N_NODES * NOPEN;  // 3.2M
    float*  f      = (float*)d_ws;
    float*  x_cur  = f;
    float*  x_old  = f + NC;
    __half* Y      = (__half*)(f + 2 * NC);     // 3.2M halves = 6.4 MB
    float*  dinv   = f + 2 * NC + NC / 2;
    int*    degi   = (int*)(dinv + N_NODES);
    int*    deg2   = degi + N_NODES;
    int*    row_st = deg2 + N_NODES;
    int*    cursor = row_st + N_NODES;
    int*    bsums  = cursor + N_NODES;
    int*    boff   = bsums + 256;
    int*    ent    = boff + 256;                // <= 2*E + 4*N ints = 13.6 MB

    dim3 B(256);
    const int GN = (N_NODES + 255) / 256;   // 196
    const int GE = (N_EDGES + 255) / 256;

    deg_init<<<GN, B, 0, stream>>>(degi, deg2);
    deg_count<<<GE, B, 0, stream>>>(I, J, degi, deg2);
    calc_dinv<<<GN, B, 0, stream>>>(degi, dinv);
    scan1<<<SCAN_BLOCKS, B, 0, stream>>>(deg2, row_st, bsums);
    scan2<<<1, B, 0, stream>>>(bsums, boff);
    scan3<<<SCAN_BLOCKS, B, 0, stream>>>(row_st, boff, cursor);
    fill_ent<<<GE, B, 0, stream>>>(I, J, cursor, ent);

    const int NB = (N_NODES + 63) / 64;     // 782
    first_layer<<<NB, B, 0, stream>>>(xn, K1, x_cur, x_old);

    float* xc = x_cur;
    float* xo = x_old;
    for (int l = 0; l < NLAYER; l++) {
        mat_y<<<NB, B, 0, stream>>>(xc, K2 + l * NOPEN * NOPEN, Y);
        gather_update<<<(N_NODES + 3) / 4, B, 0, stream>>>(Y, xc, xo, ent, row_st, deg2,
                                                           dinv, K2 + l * NOPEN * NOPEN, xo);
        float* tmp = xc; xc = xo; xo = tmp;
    }
    out_kernel<<<NB, B, 0, stream>>>(xc, Kc, (float*)d_out);
}